// Round 1
// baseline (231.611 us; speedup 1.0000x reference)
//
#include <hip/hip_runtime.h>
#include <math.h>

// SafetyConstraint: per-row CBF value.
// lie = g_pos·vel + g_quat·quat_dot + g_vel·vel_dot  (all other grad entries are 0)
// cbf = clip(clip(lie,-100,100) + 2*h, -20, 20)
//
// R1: coalesced float4 staging of the 18-float state rows through LDS.
// Old version issued 7 strided float2/scalar loads per thread (stride 72 B)
// -> ~64 cache-line probes per VMEM instr, 8 B used per probe (L1-tag bound).
// New version: block stages 256 rows (18 KB) via linear float4 copy
// (consecutive lanes -> consecutive 16 B), action as per-thread float4.
// LDS row reads are a 4-way bank conflict (stride 18 dwords) - accepted,
// costs ~1.58x on 8 LDS instrs/wave, negligible vs the coalescing win.
// 18 KB LDS -> 8 blocks/CU -> full 32-wave occupancy.

__device__ __forceinline__ float compute_cbf(
    float px, float py, float pz,
    float q0, float q1, float q2, float q3,
    float vx, float vy, float vz,
    float wx, float wy, float wz,
    float a0)
{
    const float EPS = 1e-8f;
    const float BETA = 5.0f;

    // normalized quaternion
    float nsq = q0*q0 + q1*q1 + q2*q2 + q3*q3;
    float n = sqrtf(nsq);
    float inv = 1.0f / (n + EPS);
    float qw = q0*inv, qx = q1*inv, qy = q2*inv, qz = q3*inv;

    // barriers
    float b0 = pz - 0.4f;
    float b1 = 1.6f - pz;
    float b2 = 1.0f - px*px;
    float b3 = 1.0f - py*py;
    float b4 = 0.16f - (vx*vx + vy*vy + vz*vz);
    float aqw = fabsf(qw);
    float qwc = fminf(fmaxf(aqw, 0.1f), 1.0f);
    float b5 = qwc - 0.75f;

    // softmin h = -logsumexp(-beta*b)/beta ; weights = softmax(-beta*b)
    float x0 = -BETA*b0, x1 = -BETA*b1, x2 = -BETA*b2,
          x3 = -BETA*b3, x4 = -BETA*b4, x5 = -BETA*b5;
    float m = fmaxf(fmaxf(fmaxf(x0, x1), fmaxf(x2, x3)), fmaxf(x4, x5));
    float e0 = __expf(x0 - m), e1 = __expf(x1 - m), e2 = __expf(x2 - m),
          e3 = __expf(x3 - m), e4 = __expf(x4 - m), e5 = __expf(x5 - m);
    float se = e0 + e1 + e2 + e3 + e4 + e5;
    float inv_se = 1.0f / se;
    float h = -(m + __logf(se)) / BETA;

    float w0 = e0*inv_se, w1 = e1*inv_se, w2 = e2*inv_se,
          w3 = e3*inv_se, w4 = e4*inv_se, w5 = e5*inv_se;

    // --- term 1: grad wrt pos · sdot[0:3]=vel
    float gpx = -2.0f*px*w2;
    float gpy = -2.0f*py*w3;
    float gpz = w0 - w1;
    float term1 = gpx*vx + gpy*vy + gpz*vz;

    // --- term 2: grad wrt quat_raw · quat_dot
    float qd0 = 0.5f*(-qx*wx - qy*wy - qz*wz);
    float qd1 = 0.5f*( qw*wx + qy*wz - qz*wy);
    float qd2 = 0.5f*( qw*wy + qz*wx - qx*wz);
    float qd3 = 0.5f*( qw*wz + qx*wy - qy*wx);
    // c5: d b5 / d qw (normalized) -- clip(|qw|,0.1,1): qw<1 strictly always
    float c5 = (aqw > 0.1f) ? ((q0 >= 0.0f) ? w5 : -w5) : 0.0f;
    float dot_nqd = qw*qd0 + qx*qd1 + qy*qd2 + qz*qd3;   // qhat . qd
    float invn = 1.0f / n;
    float term2 = c5 * (qd0*inv - q0*dot_nqd*inv*invn);

    // --- term 3: grad wrt vel · vel_dot = gvz * az
    float gvz = -2.0f*vz*w4;
    float thrust = fminf(fmaxf(a0, 0.0f), 0.35f);
    float R33 = fminf(fmaxf(1.0f - 2.0f*(qx*qx + qy*qy), -1.0f), 1.0f);
    float az = thrust * R33 * (1.0f / 0.027f) - 9.81f;
    float term3 = gvz * az;

    float lie = term1 + term2 + term3;
    float h_dot = fminf(fmaxf(lie, -100.0f), 100.0f);
    return fminf(fmaxf(h_dot + 2.0f*h, -20.0f), 20.0f);
}

__global__ __launch_bounds__(256) void SafetyConstraint_68238440398980_kernel(
    const float* __restrict__ state,
    const float* __restrict__ action,
    float* __restrict__ out,
    int nrows)
{
    __shared__ __align__(16) float lds[256 * 18];   // 18 KB

    const int tid = threadIdx.x;
    const long long blockStart = (long long)blockIdx.x * 256;

    if (blockStart + 256 <= nrows) {
        // ---- staged fast path: coalesced float4 copy of 256 rows -> LDS
        const float4* __restrict__ gsrc =
            reinterpret_cast<const float4*>(state + blockStart * 18);
        float4* l4 = reinterpret_cast<float4*>(lds);
        // 256 rows * 18 floats = 1152 float4 = 4*256 + 128
        #pragma unroll
        for (int j = 0; j < 4; ++j)
            l4[tid + 256 * j] = gsrc[tid + 256 * j];
        if (tid < 128)
            l4[tid + 1024] = gsrc[tid + 1024];

        // action row = exactly one float4 per thread, naturally coalesced
        float4 act = reinterpret_cast<const float4*>(action)[blockStart + tid];

        __syncthreads();

        const float* s = lds + tid * 18;           // 72 B stride, 8 B aligned
        float2 f0 = *reinterpret_cast<const float2*>(s + 0);   // px, py
        float2 f1 = *reinterpret_cast<const float2*>(s + 2);   // pz, q0
        float2 f2 = *reinterpret_cast<const float2*>(s + 4);   // q1, q2
        float2 f3 = *reinterpret_cast<const float2*>(s + 6);   // q3, vx
        float2 f4 = *reinterpret_cast<const float2*>(s + 8);   // vy, vz
        float2 f5 = *reinterpret_cast<const float2*>(s + 10);  // wx, wy
        float wz = s[12];

        float cbf = compute_cbf(f0.x, f0.y, f1.x,
                                f1.y, f2.x, f2.y, f3.x,
                                f3.y, f4.x, f4.y,
                                f5.x, f5.y, wz,
                                act.x);
        out[blockStart + tid] = cbf;
    } else {
        // ---- tail path (unused when nrows % 256 == 0): direct strided loads
        long long row = blockStart + tid;
        if (row >= nrows) return;
        const float* s = state + row * 18;
        float2 f0 = *reinterpret_cast<const float2*>(s + 0);
        float2 f1 = *reinterpret_cast<const float2*>(s + 2);
        float2 f2 = *reinterpret_cast<const float2*>(s + 4);
        float2 f3 = *reinterpret_cast<const float2*>(s + 6);
        float2 f4 = *reinterpret_cast<const float2*>(s + 8);
        float2 f5 = *reinterpret_cast<const float2*>(s + 10);
        float wz = s[12];
        float a0 = action[row * 4];

        float cbf = compute_cbf(f0.x, f0.y, f1.x,
                                f1.y, f2.x, f2.y, f3.x,
                                f3.y, f4.x, f4.y,
                                f5.x, f5.y, wz,
                                a0);
        out[row] = cbf;
    }
}

extern "C" void kernel_launch(void* const* d_in, const int* in_sizes, int n_in,
                              void* d_out, int out_size, void* d_ws, size_t ws_size,
                              hipStream_t stream) {
    const float* state  = (const float*)d_in[0];
    const float* action = (const float*)d_in[1];
    float* out = (float*)d_out;
    int nrows = in_sizes[0] / 18;
    int grid = (nrows + 255) / 256;
    SafetyConstraint_68238440398980_kernel<<<grid, 256, 0, stream>>>(state, action, out, nrows);
}